// Round 6
// baseline (48.318 us; speedup 1.0000x reference)
//
#include <hip/hip_runtime.h>
#include <hip/hip_bf16.h>
#include <string.h>

typedef __attribute__((ext_vector_type(8))) short bf16x8;
typedef __attribute__((ext_vector_type(4))) float f32x4;

namespace {
constexpr int B = 8, H = 128, W = 128, C = 128;
constexpr int MO = 9, NOFF = 81;
constexpr int ROWS = 4;          // output rows per block
constexpr int WCOLS = 16;        // output cols per block
constexpr int F2R = 12;          // staged F2 rows (4 + 2*4 halo)
constexpr int F2S = 24;          // F2 col pitch == real cols (no pad)
constexpr int SREAL = 24;        // fx = wb0-4 .. wb0+19
constexpr int CK = 32;           // channels per chunk (one MFMA K)
constexpr int NCH = C / CK;      // 4
constexpr int NT = 256;          // 4 waves
constexpr int NLD = 9;           // 12*24*8/256 staging float4 per thread
constexpr int RSTR = F2S * CK;   // 768 shorts per staged F2 row
constexpr int F2BUF = F2R * RSTR;// 9216 shorts per buffer
}

__device__ inline unsigned bf2pack(float a, float b) {
  // RTNE fp32->bf16 pair via v_cvt_pk_bf16_f32 (a = low half)
  __hip_bfloat162 h = __float22bfloat162_rn(float2{a, b});
  unsigned r;
  memcpy(&r, &h, sizeof(r));
  return r;
}

__device__ __forceinline__ f32x4 mfma16(bf16x8 a, bf16x8 b, f32x4 c) {
  return __builtin_amdgcn_mfma_f32_16x16x32_bf16(a, b, c, 0, 0, 0);
}

// Wave OM owns staged F2 rows {OM, OM+4, OM+8}; for each owned row ry it
// computes tiles for output rows r with dy = ry - r in [0,8] -> 9 tiles.
template <int OM>
__device__ __forceinline__ void compute_body(
    const float* __restrict__ F2, float* __restrict__ out,
    short* sF2, const short* sF1,
    const int* gofs, const int* lofs, unsigned okm,
    int b, int h0, int wb0, int j, int kq, int phase)
{
  f32x4 acc[9][2];
#pragma unroll
  for (int s = 0; s < 9; ++s) { acc[s][0] = {0,0,0,0}; acc[s][1] = {0,0,0,0}; }

#pragma unroll
  for (int lc = 0; lc < NCH; ++lc) {
    float4 ld[NLD];
    if (lc + 1 < NCH) {
      const int nach = (lc + 1 + phase) & 3;
#pragma unroll
      for (int it = 0; it < NLD; ++it) {
        ld[it] = *reinterpret_cast<const float4*>(F2 + gofs[it] + nach * CK);
      }
      __builtin_amdgcn_sched_barrier(0);  // loads issue before compute
    }
    const int ach = (lc + phase) & 3;

    // A fragments for all 4 output rows (fragment-major F1 LDS, contiguous)
    bf16x8 a[4];
#pragma unroll
    for (int r = 0; r < 4; ++r) {
      a[r] = *reinterpret_cast<const bf16x8*>(
          sF1 + ((r * 4 + ach) * 64 + j * 4 + kq) * 8);
    }

    const short* bbase = sF2 + (lc & 1) * F2BUF + j * CK + kq * 8;
    __builtin_amdgcn_s_setprio(1);
    int slot = 0;
#pragma unroll
    for (int rr = 0; rr < 3; ++rr) {
      const int ry = OM + rr * 4;
      const bf16x8 b0 = *reinterpret_cast<const bf16x8*>(bbase + ry * RSTR);
      const bf16x8 b1 = *reinterpret_cast<const bf16x8*>(bbase + ry * RSTR + 16 * CK);
      const int rlo = (rr == 2) ? OM : 0;
      const int rhi = (rr == 0) ? OM : 3;
#pragma unroll
      for (int r = rlo; r <= rhi; ++r) {
        acc[slot][0] = mfma16(a[r], b0, acc[slot][0]);
        acc[slot][1] = mfma16(a[r], b1, acc[slot][1]);
        ++slot;
      }
    }
    __builtin_amdgcn_s_setprio(0);

    if (lc + 1 < NCH) {
      __builtin_amdgcn_sched_barrier(0);  // pack/store stays after MFMA
#pragma unroll
      for (int it = 0; it < NLD; ++it) {
        if ((okm >> it) & 1u) {
          uint2 p;
          p.x = bf2pack(ld[it].x, ld[it].y);
          p.y = bf2pack(ld[it].z, ld[it].w);
          *reinterpret_cast<uint2*>(&sF2[((lc + 1) & 1) * F2BUF + lofs[it]]) = p;
        }
      }
      __syncthreads();
    }
  }

  // Epilogue: band extract (F1 pre-scaled by 1/128), leaky_relu, store.
  // D layout: n = j (F2 staged col s = j+16t), m = kq*4+reg (pixel i);
  // dxi = s - i.
  int slot = 0;
#pragma unroll
  for (int rr = 0; rr < 3; ++rr) {
    const int ry = OM + rr * 4;
    const int rlo = (rr == 2) ? OM : 0;
    const int rhi = (rr == 0) ? OM : 3;
#pragma unroll
    for (int r = rlo; r <= rhi; ++r) {
      const int dy = ry - r;
      float* outb = out + (((size_t)b * H + h0 + r) * W + wb0) * NOFF + dy * MO;
#pragma unroll
      for (int t = 0; t < 2; ++t) {
#pragma unroll
        for (int reg = 0; reg < 4; ++reg) {
          const int i = kq * 4 + reg;
          const int dxi = j + t * 16 - i;
          if (dxi >= 0 && dxi <= 8) {
            float m = acc[slot][t][reg];
            m = fmaxf(m, 0.1f * m);  // leaky_relu(0.1)
            outb[(size_t)i * NOFF + dxi] = m;
          }
        }
      }
      ++slot;
    }
  }
}

__global__ __launch_bounds__(NT, 3) void costvol_kernel(
    const float* __restrict__ F1, const float* __restrict__ F2,
    float* __restrict__ out)
{
  __shared__ __align__(16) short sF2[2 * F2BUF];   // 36 KB (dbuf, bf16)
  __shared__ __align__(16) short sF1[4 * 4 * 64 * 8]; // 16 KB fragment-major

  const int lin  = blockIdx.x;
  const int b    = lin & 7;            // one batch per XCD
  const int tile = lin >> 3;
  const int rt   = tile & 31;
  const int wt   = tile >> 5;          // 0..7
  const int h0   = rt * ROWS;
  const int wb0  = wt * WCOLS;
  const int phase = tile & 3;          // chunk stagger across same-CU blocks

  const int tid  = threadIdx.x;
  const int wv   = tid >> 6;
  const int lane = tid & 63;
  const int j    = lane & 15;
  const int kq   = lane >> 4;

  // ---- loop-invariant F2 staging decode
  int gofs[NLD]; int lofs[NLD]; unsigned okm = 0;
#pragma unroll
  for (int it = 0; it < NLD; ++it) {
    const int idx  = tid + it * NT;     // 0..2303
    const int kg   = idx & 7;
    const int slot = idx >> 3;          // 0..287
    const int ry   = slot / SREAL;
    const int s    = slot - ry * SREAL;
    const int fy   = h0 - 4 + ry;
    const int fx   = wb0 - 4 + s;
    const bool ok  = ((unsigned)fy < (unsigned)H) && ((unsigned)fx < (unsigned)W);
    okm |= (unsigned)ok << it;
    gofs[it] = ok ? (((b * H + fy) * W + fx) * C + kg * 4) : 0;
    lofs[it] = (ry * F2S + s) * CK + kg * 4;
  }

  // ---- prologue: issue F2 chunk-`phase` loads, stage F1, zero OOB slots
  {
    float4 ld[NLD];
#pragma unroll
    for (int it = 0; it < NLD; ++it) {
      ld[it] = *reinterpret_cast<const float4*>(F2 + gofs[it] + phase * CK);
    }
    __builtin_amdgcn_sched_barrier(0);

    // F1 tile 4x16x128 -> bf16/128 in fragment-major LDS
    const int fr  = tid >> 6;
    const int fpx = (tid >> 2) & 15;
    const int fcg = tid & 3;
    const float* f1p =
        F1 + (((size_t)b * H + h0 + fr) * W + wb0 + fpx) * C + fcg * 32;
    float4 u[8];
#pragma unroll
    for (int q = 0; q < 8; ++q) u[q] = *reinterpret_cast<const float4*>(f1p + q * 4);

    // zero OOB slots of BOTH buffers once (writes to them are skipped later)
#pragma unroll
    for (int it = 0; it < NLD; ++it) {
      if (!((okm >> it) & 1u)) {
        *reinterpret_cast<uint2*>(&sF2[lofs[it]]) = uint2{0u, 0u};
        *reinterpret_cast<uint2*>(&sF2[F2BUF + lofs[it]]) = uint2{0u, 0u};
      }
    }
    // pack+store F2 chunk `phase` into buffer 0
#pragma unroll
    for (int it = 0; it < NLD; ++it) {
      if ((okm >> it) & 1u) {
        uint2 p;
        p.x = bf2pack(ld[it].x, ld[it].y);
        p.y = bf2pack(ld[it].z, ld[it].w);
        *reinterpret_cast<uint2*>(&sF2[lofs[it]]) = p;
      }
    }
    // pack F1 (pre-scaled by 1/128) into fragment-major layout
    constexpr float S = 0.0078125f;
#pragma unroll
    for (int kqq = 0; kqq < 4; ++kqq) {
      uint4 q;
      q.x = bf2pack(u[2 * kqq].x * S, u[2 * kqq].y * S);
      q.y = bf2pack(u[2 * kqq].z * S, u[2 * kqq].w * S);
      q.z = bf2pack(u[2 * kqq + 1].x * S, u[2 * kqq + 1].y * S);
      q.w = bf2pack(u[2 * kqq + 1].z * S, u[2 * kqq + 1].w * S);
      *reinterpret_cast<uint4*>(
          &sF1[((fr * 4 + fcg) * 64 + fpx * 4 + kqq) * 8]) = q;
    }
    __syncthreads();
  }

  switch (wv) {
    case 0: compute_body<0>(F2, out, sF2, sF1, gofs, lofs, okm, b, h0, wb0, j, kq, phase); break;
    case 1: compute_body<1>(F2, out, sF2, sF1, gofs, lofs, okm, b, h0, wb0, j, kq, phase); break;
    case 2: compute_body<2>(F2, out, sF2, sF1, gofs, lofs, okm, b, h0, wb0, j, kq, phase); break;
    default: compute_body<3>(F2, out, sF2, sF1, gofs, lofs, okm, b, h0, wb0, j, kq, phase); break;
  }
}

extern "C" void kernel_launch(void* const* d_in, const int* in_sizes, int n_in,
                              void* d_out, int out_size, void* d_ws, size_t ws_size,
                              hipStream_t stream) {
  const float* F1 = (const float*)d_in[0];
  const float* F2 = (const float*)d_in[1];
  float* out = (float*)d_out;
  dim3 grid(B * (H / ROWS) * (W / WCOLS));  // 2048 blocks
  dim3 block(NT);                           // 256 threads = 4 waves
  hipLaunchKernelGGL(costvol_kernel, grid, block, 0, stream, F1, F2, out);
}